// Round 1
// baseline (18.267 us; speedup 1.0000x reference)
//
#include <hip/hip_runtime.h>

// MonoDispExp: per-pixel affine flow-consistency fit on a 3x3 neighborhood.
// flow: (B=4, 2, H=256, W=832) float32.
// Outputs (concatenated in d_out as float32):
//   [0 .. BHW)   mask  (b,h,w)  as 0.0/1.0
//   [BHW..2BHW)  exp   (b,1,h,w)
//
// Reference semantics:
//   pref = (x, y) grid; ptar = pref + flow.
//   3x3 unfold with ZERO padding, then subtract center value:
//     in-range neighbor (di,dj):  pr = (dj, di)
//                                 pt = (dj + fx(n)-fx(c), di + fy(n)-fy(c))
//     out-of-range:               pr = (-x, -y)
//                                 pt = (-(x+fx(c)), -(y+fy(c)))
//   pp = pr pr^T (2x2), det = clip(det, 1e-10); ppinv = adj/det
//   aff = (pt pr^T) @ ppinv
//   error = mean_k || aff*pr_k - pt_k ||
//   exp = sqrt(clip(|det(aff)|, 1e-10))
//   mask = (exp>0.5) & (exp<2.0) & (error<0.1)
//   exp_out = error>0.1 ? 1.0 : clip(exp, 0.5, 2.0)

#define BB 4
#define HH 256
#define WW 832

__global__ __launch_bounds__(256) void monodisp_kernel(
    const float* __restrict__ flow,
    float* __restrict__ out_mask,
    float* __restrict__ out_exp) {
  const int HW = HH * WW;
  int idx = blockIdx.x * blockDim.x + threadIdx.x;
  if (idx >= BB * HW) return;

  int x = idx % WW;
  int t = idx / WW;
  int y = t % HH;
  int b = t / HH;

  const float* __restrict__ fx = flow + (size_t)(b * 2 + 0) * HW;
  const float* __restrict__ fy = flow + (size_t)(b * 2 + 1) * HW;

  const float fxc = fx[y * WW + x];
  const float fyc = fy[y * WW + x];

  float pp00 = 0.f, pp01 = 0.f, pp11 = 0.f;
  float m00 = 0.f, m01 = 0.f, m10 = 0.f, m11 = 0.f;

  float prxs[9], prys[9], ptxs[9], ptys[9];

#pragma unroll
  for (int di = -1; di <= 1; ++di) {
#pragma unroll
    for (int dj = -1; dj <= 1; ++dj) {
      const int k = (di + 1) * 3 + (dj + 1);
      const int yy = y + di;
      const int xx = x + dj;
      const bool in = (yy >= 0) && (yy < HH) && (xx >= 0) && (xx < WW);
      float prx, pry, ptx, pty;
      if (in) {
        prx = (float)dj;
        pry = (float)di;
        ptx = (float)dj + (fx[yy * WW + xx] - fxc);
        pty = (float)di + (fy[yy * WW + xx] - fyc);
      } else {
        prx = -(float)x;
        pry = -(float)y;
        ptx = -((float)x + fxc);
        pty = -((float)y + fyc);
      }
      prxs[k] = prx; prys[k] = pry; ptxs[k] = ptx; ptys[k] = pty;
      pp00 += prx * prx;
      pp01 += prx * pry;
      pp11 += pry * pry;
      m00 += ptx * prx;
      m01 += ptx * pry;
      m10 += pty * prx;
      m11 += pty * pry;
    }
  }

  float det = pp00 * pp11 - pp01 * pp01;
  det = fmaxf(det, 1e-10f);

  // ppinv = adj / det, elementwise first (match reference op order)
  const float i00 = pp11 / det;
  const float i01 = -pp01 / det;
  const float i10 = -pp01 / det;
  const float i11 = pp00 / det;

  const float a00 = m00 * i00 + m01 * i10;
  const float a01 = m00 * i01 + m01 * i11;
  const float a10 = m10 * i00 + m11 * i10;
  const float a11 = m10 * i01 + m11 * i11;

  float errsum = 0.f;
#pragma unroll
  for (int k = 0; k < 9; ++k) {
    const float rx = a00 * prxs[k] + a01 * prys[k] - ptxs[k];
    const float ry = a10 * prxs[k] + a11 * prys[k] - ptys[k];
    errsum += sqrtf(rx * rx + ry * ry);
  }
  const float error = errsum / 9.0f;

  float avol = fabsf(a00 * a11 - a10 * a01);
  avol = fmaxf(avol, 1e-10f);
  const float ex = sqrtf(avol);

  const bool mask = (ex > 0.5f) && (ex < 2.0f) && (error < 0.1f);
  const float exp_out = (error > 0.1f) ? 1.0f : fminf(fmaxf(ex, 0.5f), 2.0f);

  out_mask[idx] = mask ? 1.0f : 0.0f;
  out_exp[idx] = exp_out;
}

extern "C" void kernel_launch(void* const* d_in, const int* in_sizes, int n_in,
                              void* d_out, int out_size, void* d_ws, size_t ws_size,
                              hipStream_t stream) {
  (void)in_sizes; (void)n_in; (void)d_ws; (void)ws_size; (void)out_size;
  const float* flow = (const float*)d_in[0];
  float* out = (float*)d_out;
  float* out_mask = out;
  float* out_exp = out + (size_t)BB * HH * WW;

  const int total = BB * HH * WW;
  const int block = 256;
  const int grid = (total + block - 1) / block;
  monodisp_kernel<<<grid, block, 0, stream>>>(flow, out_mask, out_exp);
}

// Round 2
// 14.019 us; speedup vs baseline: 1.3030x; 1.3030x over previous
//
#include <hip/hip_runtime.h>

// MonoDispExp: per-pixel affine flow-consistency fit on a 3x3 neighborhood.
// flow: (B=4, 2, H=256, W=832) float32.
// Outputs (concatenated in d_out as float32):
//   [0 .. BHW)   mask  (b,h,w)  as 0.0/1.0
//   [BHW..2BHW)  exp   (b,1,h,w)
//
// Interior pixels (98.9%): pr == (dj,di) exactly -> pp = [[6,0],[0,6]],
// det = 36, ppinv = diag(1/6). aff = M/6 with M entries = signed sums of
// pt values (weights 0/+-1). Residual center term is exactly 0 -> skipped.
// This is bit-equivalent to the reference arithmetic (mults by exact 0/+-1;
// fp32(6/36) == fp32(1/6)).
// Edge pixels: general path (zero-pad-minus-center semantics), as validated
// in round 1 (absmax 0.0).

#define BB 4
#define HH 256
#define WW 832
#define HWsz (HH * WW)

__device__ __forceinline__ float fsqrt(float x) { return __builtin_amdgcn_sqrtf(x); }

__global__ __launch_bounds__(256) void monodisp_kernel(
    const float* __restrict__ flow,
    float* __restrict__ out_mask,
    float* __restrict__ out_exp) {
  const int idx = blockIdx.x * 256 + threadIdx.x;

  const int x = idx % WW;
  const int t = idx / WW;
  const int y = t % HH;
  const int b = t / HH;

  const float* __restrict__ fx = flow + (b * 2 + 0) * HWsz;
  const float* __restrict__ fy = flow + (b * 2 + 1) * HWsz;
  const int o = y * WW + x;

  float a00, a01, a10, a11, error;

  const bool interior = (x >= 1) && (x < WW - 1) && (y >= 1) && (y < HH - 1);
  if (interior) {
    // ---- fast path: 18 loads, constant pp ----
    const float fx00 = fx[o - WW - 1], fx01 = fx[o - WW], fx02 = fx[o - WW + 1];
    const float fx10 = fx[o - 1],      fx11 = fx[o],      fx12 = fx[o + 1];
    const float fx20 = fx[o + WW - 1], fx21 = fx[o + WW], fx22 = fx[o + WW + 1];
    const float fy00 = fy[o - WW - 1], fy01 = fy[o - WW], fy02 = fy[o - WW + 1];
    const float fy10 = fy[o - 1],      fy11 = fy[o],      fy12 = fy[o + 1];
    const float fy20 = fy[o + WW - 1], fy21 = fy[o + WW], fy22 = fy[o + WW + 1];

    // pt_k = (dj,di) + (f_n - f_c); k = (di+1)*3 + (dj+1); k=4 is (0,0).
    const float ptx0 = -1.f + (fx00 - fx11), ptx1 = (fx01 - fx11), ptx2 = 1.f + (fx02 - fx11);
    const float ptx3 = -1.f + (fx10 - fx11),                       ptx5 = 1.f + (fx12 - fx11);
    const float ptx6 = -1.f + (fx20 - fx11), ptx7 = (fx21 - fx11), ptx8 = 1.f + (fx22 - fx11);
    const float pty0 = -1.f + (fy00 - fy11), pty1 = -1.f + (fy01 - fy11), pty2 = -1.f + (fy02 - fy11);
    const float pty3 = (fy10 - fy11),                                     pty5 = (fy12 - fy11);
    const float pty6 = 1.f + (fy20 - fy11), pty7 = 1.f + (fy21 - fy11),  pty8 = 1.f + (fy22 - fy11);

    // M = pt * pr^T, pr columns are (dj,di) with dj,di in {-1,0,1}
    const float m00 = (ptx2 + ptx5 + ptx8) - (ptx0 + ptx3 + ptx6);
    const float m01 = (ptx6 + ptx7 + ptx8) - (ptx0 + ptx1 + ptx2);
    const float m10 = (pty2 + pty5 + pty8) - (pty0 + pty3 + pty6);
    const float m11 = (pty6 + pty7 + pty8) - (pty0 + pty1 + pty2);

    const float inv6 = 1.0f / 6.0f;  // == fp32(6/36), matches reference adj/det
    a00 = m00 * inv6;
    a01 = m01 * inv6;
    a10 = m10 * inv6;
    a11 = m11 * inv6;

    // aff * pr combos (exact: mults by 0/+-1)
    const float sxp = a00 + a01, sxm = a00 - a01;
    const float syp = a10 + a11, sym = a10 - a11;

    float errsum = 0.f;
    {
      float rx, ry;
      rx = -sxp - ptx0; ry = -syp - pty0; errsum += fsqrt(rx * rx + ry * ry);  // k0 (-1,-1)
      rx = -a01 - ptx1; ry = -a11 - pty1; errsum += fsqrt(rx * rx + ry * ry);  // k1 ( 0,-1)
      rx =  sxm - ptx2; ry =  sym - pty2; errsum += fsqrt(rx * rx + ry * ry);  // k2 ( 1,-1)
      rx = -a00 - ptx3; ry = -a10 - pty3; errsum += fsqrt(rx * rx + ry * ry);  // k3 (-1, 0)
      // k4 (0,0): residual exactly 0
      rx =  a00 - ptx5; ry =  a10 - pty5; errsum += fsqrt(rx * rx + ry * ry);  // k5 ( 1, 0)
      rx = -sxm - ptx6; ry = -sym - pty6; errsum += fsqrt(rx * rx + ry * ry);  // k6 (-1, 1)
      rx =  a01 - ptx7; ry =  a11 - pty7; errsum += fsqrt(rx * rx + ry * ry);  // k7 ( 0, 1)
      rx =  sxp - ptx8; ry =  syp - pty8; errsum += fsqrt(rx * rx + ry * ry);  // k8 ( 1, 1)
    }
    error = errsum / 9.0f;
  } else {
    // ---- general path: image-border pixels only ----
    const float fxc = fx[o];
    const float fyc = fy[o];

    float pp00 = 0.f, pp01 = 0.f, pp11 = 0.f;
    float m00 = 0.f, m01 = 0.f, m10 = 0.f, m11 = 0.f;
    float prxs[9], prys[9], ptxs[9], ptys[9];

#pragma unroll
    for (int di = -1; di <= 1; ++di) {
#pragma unroll
      for (int dj = -1; dj <= 1; ++dj) {
        const int k = (di + 1) * 3 + (dj + 1);
        const int yy = y + di;
        const int xx = x + dj;
        const bool in = (yy >= 0) && (yy < HH) && (xx >= 0) && (xx < WW);
        float prx, pry, ptx, pty;
        if (in) {
          prx = (float)dj;
          pry = (float)di;
          ptx = (float)dj + (fx[yy * WW + xx] - fxc);
          pty = (float)di + (fy[yy * WW + xx] - fyc);
        } else {
          prx = -(float)x;
          pry = -(float)y;
          ptx = -((float)x + fxc);
          pty = -((float)y + fyc);
        }
        prxs[k] = prx; prys[k] = pry; ptxs[k] = ptx; ptys[k] = pty;
        pp00 += prx * prx;
        pp01 += prx * pry;
        pp11 += pry * pry;
        m00 += ptx * prx;
        m01 += ptx * pry;
        m10 += pty * prx;
        m11 += pty * pry;
      }
    }

    float det = pp00 * pp11 - pp01 * pp01;
    det = fmaxf(det, 1e-10f);

    const float i00 = pp11 / det;
    const float i01 = -pp01 / det;
    const float i10 = -pp01 / det;
    const float i11 = pp00 / det;

    a00 = m00 * i00 + m01 * i10;
    a01 = m00 * i01 + m01 * i11;
    a10 = m10 * i00 + m11 * i10;
    a11 = m10 * i01 + m11 * i11;

    float errsum = 0.f;
#pragma unroll
    for (int k = 0; k < 9; ++k) {
      const float rx = a00 * prxs[k] + a01 * prys[k] - ptxs[k];
      const float ry = a10 * prxs[k] + a11 * prys[k] - ptys[k];
      errsum += fsqrt(rx * rx + ry * ry);
    }
    error = errsum / 9.0f;
  }

  float avol = fabsf(a00 * a11 - a10 * a01);
  avol = fmaxf(avol, 1e-10f);
  const float ex = fsqrt(avol);

  const bool mask = (ex > 0.5f) && (ex < 2.0f) && (error < 0.1f);
  const float exp_out = (error > 0.1f) ? 1.0f : fminf(fmaxf(ex, 0.5f), 2.0f);

  out_mask[idx] = mask ? 1.0f : 0.0f;
  out_exp[idx] = exp_out;
}

extern "C" void kernel_launch(void* const* d_in, const int* in_sizes, int n_in,
                              void* d_out, int out_size, void* d_ws, size_t ws_size,
                              hipStream_t stream) {
  (void)in_sizes; (void)n_in; (void)d_ws; (void)ws_size; (void)out_size;
  const float* flow = (const float*)d_in[0];
  float* out = (float*)d_out;
  float* out_mask = out;
  float* out_exp = out + (size_t)BB * HH * WW;

  const int total = BB * HH * WW;          // 851968 = 3328 * 256 exactly
  const int block = 256;
  const int grid = total / block;
  monodisp_kernel<<<grid, block, 0, stream>>>(flow, out_mask, out_exp);
}